// Round 4
// baseline (1851.678 us; speedup 1.0000x reference)
//
#include <hip/hip_runtime.h>
#include <hip/hip_bf16.h>

// Problem constants: B=4, N=2048, D=1024, H=16, dh=64
// ROUND 4: inputs/outputs are FP32 (per reference setup_inputs — jnp.float32).
// Rounds 1-3 read fp32 buffers as bf16 -> pseudo-NaN bf16 patterns -> NaN out.
#define SEQ   2048
#define DIM   1024
#define HEADS 16
#define DH    64
#define MROWS 8192            // B*N
#define K3    3072            // 3*D
#define NEGV  (-32767.0f)     // -2^15+1, matches reference mask constant
#define SCALE 8.0f            // sqrt(dh) — reference MULTIPLIES by sqrt(d)

typedef __attribute__((ext_vector_type(8))) short bf16x8;
typedef __attribute__((ext_vector_type(4))) float f32x4;

// bf16 round-to-nearest-even via bit ops (inputs finite; no NaN path needed)
__device__ inline short f2bf(float x) {
  union { float f; unsigned u; } v; v.f = x;
  unsigned r = v.u + 0x7FFF + ((v.u >> 16) & 1);
  return (short)(r >> 16);
}
__device__ inline float bf2f(short s) {
  union { float f; unsigned u; } v; v.u = ((unsigned)(unsigned short)s) << 16;
  return v.f;
}
// split x = hi + lo (both bf16); residual error ~2^-18 relative
__device__ inline void cvt_split8(const float4 a, const float4 b,
                                  bf16x8& hi, bf16x8& lo) {
  const float f[8] = {a.x, a.y, a.z, a.w, b.x, b.y, b.z, b.w};
#pragma unroll
  for (int i = 0; i < 8; i++) {
    const short h = f2bf(f[i]);
    hi[i] = h;
    lo[i] = f2bf(f[i] - bf2f(h));
  }
}

// ---------------------------------------------------------------------------
// Kernel 1: qkv = concat(q,k,v) @ w_qkv^T + b_qkv   (8192 x 3072, fp32 out)
// 128x128 tile, BK=32, 4 waves. Q/K output columns (Nb<2048) use split-bf16
// 3-MFMA compensation (hi*hi + hi*lo + lo*hi) — scores are x8-scaled and
// softmax-sensitive; 1-pass bf16 would miss the 2% threshold. V columns 1-pass.
// ---------------------------------------------------------------------------
__global__ __launch_bounds__(256) void qkv_gemm(
    const float* __restrict__ q,
    const float* __restrict__ k,
    const float* __restrict__ v,
    const float* __restrict__ wqkv,   // (3072, 3072) row-major fp32
    const float* __restrict__ bqkv,   // (3072) fp32
    float* __restrict__ qkvo)         // (8192, 3072) fp32
{
  __shared__ short Ash[128 * 32];
  __shared__ short Asl[128 * 32];
  __shared__ short Bsh[128 * 32];
  __shared__ short Bsl[128 * 32];

  const int t    = threadIdx.x;
  const int lane = t & 63;
  const int wv   = t >> 6;
  const int Mb   = blockIdx.y * 128;
  const int Nb   = blockIdx.x * 128;
  const bool prec = (Nb < 2 * DIM);   // q,k columns need compensation
  const int wr   = (wv >> 1) * 64;
  const int wc   = (wv & 1) * 64;
  const int l15  = lane & 15;
  const int lq   = lane >> 4;

  // staging map: thread covers row (it*64 + wv*16 + lane/4), cols (lane&3)*8..+8
  const int srow = wv * 16 + (lane >> 2);
  const int scol = (lane & 3) * 8;

  f32x4 acc[4][4];
#pragma unroll
  for (int i = 0; i < 4; i++)
#pragma unroll
    for (int j = 0; j < 4; j++) acc[i][j] = (f32x4){0.f, 0.f, 0.f, 0.f};

  for (int k0 = 0; k0 < K3; k0 += 32) {
    // concat(q,k,v): each 32-wide K tile lies wholly inside one source
    const float* src = (k0 < DIM) ? q : ((k0 < 2 * DIM) ? k : v);
    const int koff = (k0 & (DIM - 1)) + scol;

    bf16x8 ah[2], al[2], bh[2], bl[2];
#pragma unroll
    for (int it = 0; it < 2; ++it) {
      const float* ap = src + (size_t)(Mb + it * 64 + srow) * DIM + koff;
      cvt_split8(*(const float4*)(ap), *(const float4*)(ap + 4), ah[it], al[it]);
      const float* bp = wqkv + (size_t)(Nb + it * 64 + srow) * K3 + k0 + scol;
      cvt_split8(*(const float4*)(bp), *(const float4*)(bp + 4), bh[it], bl[it]);
    }
    __syncthreads();                 // prior iteration's fragment reads done
#pragma unroll
    for (int it = 0; it < 2; ++it) {
      *(bf16x8*)(Ash + (it * 64 + srow) * 32 + scol) = ah[it];
      *(bf16x8*)(Bsh + (it * 64 + srow) * 32 + scol) = bh[it];
      if (prec) {
        *(bf16x8*)(Asl + (it * 64 + srow) * 32 + scol) = al[it];
        *(bf16x8*)(Bsl + (it * 64 + srow) * 32 + scol) = bl[it];
      }
    }
    __syncthreads();                 // tile visible

    bf16x8 afh[4], bfh[4];
#pragma unroll
    for (int i = 0; i < 4; i++)
      afh[i] = *(const bf16x8*)(Ash + (wr + i * 16 + l15) * 32 + lq * 8);
#pragma unroll
    for (int j = 0; j < 4; j++)
      bfh[j] = *(const bf16x8*)(Bsh + (wc + j * 16 + l15) * 32 + lq * 8);
#pragma unroll
    for (int i = 0; i < 4; i++)
#pragma unroll
      for (int j = 0; j < 4; j++)
        acc[i][j] = __builtin_amdgcn_mfma_f32_16x16x32_bf16(afh[i], bfh[j], acc[i][j], 0, 0, 0);

    if (prec) {
      bf16x8 afl[4], bfl[4];
#pragma unroll
      for (int i = 0; i < 4; i++)
        afl[i] = *(const bf16x8*)(Asl + (wr + i * 16 + l15) * 32 + lq * 8);
#pragma unroll
      for (int j = 0; j < 4; j++)
        bfl[j] = *(const bf16x8*)(Bsl + (wc + j * 16 + l15) * 32 + lq * 8);
#pragma unroll
      for (int i = 0; i < 4; i++)
#pragma unroll
        for (int j = 0; j < 4; j++) {
          acc[i][j] = __builtin_amdgcn_mfma_f32_16x16x32_bf16(afh[i], bfl[j], acc[i][j], 0, 0, 0);
          acc[i][j] = __builtin_amdgcn_mfma_f32_16x16x32_bf16(afl[i], bfh[j], acc[i][j], 0, 0, 0);
        }
    }
  }

  // epilogue: C/D layout col=lane&15, row=(lane>>4)*4+reg  [m89/m91 verified]
#pragma unroll
  for (int j = 0; j < 4; j++) {
    const int col = Nb + wc + j * 16 + l15;
    const float bias = bqkv[col];
#pragma unroll
    for (int i = 0; i < 4; i++) {
#pragma unroll
      for (int r = 0; r < 4; r++) {
        const int row = Mb + wr + i * 16 + lq * 4 + r;
        qkvo[(size_t)row * K3 + col] = acc[i][j][r] + bias;
      }
    }
  }
}

// ---------------------------------------------------------------------------
// Kernel 2: flash-style causal attention, fp32 VALU, full barrier discipline.
// One block = (b, h, 64-query tile). 32-key tiles staged in LDS.
// ---------------------------------------------------------------------------
__global__ __launch_bounds__(256) void attn_fwd(
    const float* __restrict__ qkv,          // (8192, 3072) fp32
    __hip_bfloat16* __restrict__ attno)     // (8192, 1024) bf16
{
  const int bx = blockIdx.x;
  const int qt = bx & 31;            // N/64 = 32 query tiles
  const int h  = (bx >> 5) & 15;
  const int b  = bx >> 9;
  const int qb = qt * 64;

  __shared__ float Qs[64 * 68];
  __shared__ float Ks[32 * 68];
  __shared__ float Vs[32 * 68];
  __shared__ float Ss[64 * 36];

  const int t = threadIdx.x;
  const size_t rowBase = (size_t)b * SEQ;

  // stage Q tile (64 x 64)
  {
    const float* qp = qkv + (rowBase + qb) * K3 + h * DH;
#pragma unroll
    for (int it = 0; it < 4; ++it) {
      const int idx = it * 1024 + t * 4;
      const int r = idx >> 6, c = idx & 63;
      *(float4*)(Qs + r * 68 + c) = *(const float4*)(qp + (size_t)r * K3 + c);
    }
  }

  const int rp = (t >> 3) * 2;       // QK: rows rp, rp+1
  const int c0 = t & 7;              // QK: keys c0 + 8j
  const int r  = t >> 2;             // softmax/PV: row
  const int cs = (t & 3) * 8;        // softmax: col block
  const int d0 = (t & 3) * 16;       // PV: dim block

  float m_i = -1e30f, l_i = 0.f;
  float O[16];
#pragma unroll
  for (int u = 0; u < 16; u++) O[u] = 0.f;

  const int nkt = qt * 2 + 2;        // causal: keys <= qb+63
  for (int kt = 0; kt < nkt; ++kt) {
    const int kb = kt * 32;
    __syncthreads();                 // prev iter done reading Ks/Vs (and Q ready)
    {
      const float* kp = qkv + (rowBase + kb) * K3 + DIM + h * DH;
      const float* vp = qkv + (rowBase + kb) * K3 + 2 * DIM + h * DH;
#pragma unroll
      for (int it = 0; it < 2; ++it) {
        const int idx = it * 1024 + t * 4;
        const int rr = idx >> 6, cc = idx & 63;
        *(float4*)(Ks + rr * 68 + cc) = *(const float4*)(kp + (size_t)rr * K3 + cc);
        *(float4*)(Vs + rr * 68 + cc) = *(const float4*)(vp + (size_t)rr * K3 + cc);
      }
    }
    __syncthreads();

    // ---- S = Q K^T (64x32), 2x4 register tile per thread ----
    float s[2][4] = {{0.f, 0.f, 0.f, 0.f}, {0.f, 0.f, 0.f, 0.f}};
#pragma unroll
    for (int d4 = 0; d4 < DH; d4 += 4) {
      const float4 qa0 = *(const float4*)(Qs + rp * 68 + d4);
      const float4 qa1 = *(const float4*)(Qs + (rp + 1) * 68 + d4);
#pragma unroll
      for (int j = 0; j < 4; ++j) {
        const float4 kv = *(const float4*)(Ks + (c0 + 8 * j) * 68 + d4);
        s[0][j] += qa0.x * kv.x + qa0.y * kv.y + qa0.z * kv.z + qa0.w * kv.w;
        s[1][j] += qa1.x * kv.x + qa1.y * kv.y + qa1.z * kv.z + qa1.w * kv.w;
      }
    }
#pragma unroll
    for (int i = 0; i < 2; i++)
#pragma unroll
      for (int j = 0; j < 4; j++) {
        const int rr = rp + i, cc = c0 + 8 * j;
        float sv = s[i][j] * SCALE;
        if (kb + cc > qb + rr) sv = NEGV;   // causal mask
        Ss[rr * 36 + cc] = sv;
      }
    __syncthreads();                 // scores visible to softmax phase

    // ---- online softmax for row r (4 lanes per row via shfl_xor 1,2) ----
    float pvb[8];
    float mt = -1e30f;
#pragma unroll
    for (int u = 0; u < 8; u++) { pvb[u] = Ss[r * 36 + cs + u]; mt = fmaxf(mt, pvb[u]); }
    mt = fmaxf(mt, __shfl_xor(mt, 1));
    mt = fmaxf(mt, __shfl_xor(mt, 2));
    const float m_new = fmaxf(m_i, mt);
    const float alpha = __expf(m_i - m_new);
    float ls = 0.f;
#pragma unroll
    for (int u = 0; u < 8; u++) { pvb[u] = __expf(pvb[u] - m_new); ls += pvb[u]; }
    ls += __shfl_xor(ls, 1);
    ls += __shfl_xor(ls, 2);
    l_i = l_i * alpha + ls;
    m_i = m_new;
#pragma unroll
    for (int u = 0; u < 8; u++) Ss[r * 36 + cs + u] = pvb[u];
#pragma unroll
    for (int u = 0; u < 16; u++) O[u] *= alpha;
    __syncthreads();                 // normalized P visible to PV phase

    // ---- O += P V (row r, dims d0..d0+15); P via scalar broadcast reads ----
#pragma unroll 4
    for (int c = 0; c < 32; ++c) {
      const float p = Ss[r * 36 + c];
      const float* vrow = Vs + c * 68 + d0;
#pragma unroll
      for (int w4 = 0; w4 < 4; ++w4) {
        const float4 vv = *(const float4*)(vrow + 4 * w4);
        O[4 * w4 + 0] += p * vv.x;
        O[4 * w4 + 1] += p * vv.y;
        O[4 * w4 + 2] += p * vv.z;
        O[4 * w4 + 3] += p * vv.w;
      }
    }
  }

  const float inv = 1.0f / l_i;
  __hip_bfloat16* op = attno + (rowBase + qb + r) * DIM + h * DH + d0;
#pragma unroll
  for (int u = 0; u < 16; u++) op[u] = __float2bfloat16(O[u] * inv);
}

// ---------------------------------------------------------------------------
// Kernel 3: out = attn @ w_out^T + b_out   (8192 x 1024, fp32 out)
// attn is bf16 (ws); w_out fp32 -> 1-pass bf16 (error ~1e-3, within budget).
// ---------------------------------------------------------------------------
__global__ __launch_bounds__(256) void out_gemm(
    const __hip_bfloat16* __restrict__ a,    // (8192, 1024) attn, bf16
    const float* __restrict__ wo,            // (1024, 1024) fp32
    const float* __restrict__ bo,            // (1024) fp32
    float* __restrict__ out)                 // (8192, 1024) fp32
{
  __shared__ short As[128 * 32];
  __shared__ short Bs[128 * 32];

  const int t    = threadIdx.x;
  const int lane = t & 63;
  const int wv   = t >> 6;
  const int Mb   = blockIdx.y * 128;
  const int Nb   = blockIdx.x * 128;
  const int wr   = (wv >> 1) * 64;
  const int wc   = (wv & 1) * 64;
  const int l15  = lane & 15;
  const int lq   = lane >> 4;
  const int srow = wv * 16 + (lane >> 2);
  const int scol = (lane & 3) * 8;

  f32x4 acc[4][4];
#pragma unroll
  for (int i = 0; i < 4; i++)
#pragma unroll
    for (int j = 0; j < 4; j++) acc[i][j] = (f32x4){0.f, 0.f, 0.f, 0.f};

  for (int k0 = 0; k0 < DIM; k0 += 32) {
    bf16x8 areg[2], breg[2];
#pragma unroll
    for (int it = 0; it < 2; ++it) {
      areg[it] = *(const bf16x8*)(a + (size_t)(Mb + it * 64 + srow) * DIM + k0 + scol);
      const float* bp = wo + (size_t)(Nb + it * 64 + srow) * DIM + k0 + scol;
      const float4 b0 = *(const float4*)(bp);
      const float4 b1 = *(const float4*)(bp + 4);
      const float bf8[8] = {b0.x, b0.y, b0.z, b0.w, b1.x, b1.y, b1.z, b1.w};
#pragma unroll
      for (int e = 0; e < 8; e++) breg[it][e] = f2bf(bf8[e]);
    }
    __syncthreads();
#pragma unroll
    for (int it = 0; it < 2; ++it) {
      *(bf16x8*)(As + (it * 64 + srow) * 32 + scol) = areg[it];
      *(bf16x8*)(Bs + (it * 64 + srow) * 32 + scol) = breg[it];
    }
    __syncthreads();

    bf16x8 af[4], bfr[4];
#pragma unroll
    for (int i = 0; i < 4; i++)
      af[i] = *(const bf16x8*)(As + (wr + i * 16 + l15) * 32 + lq * 8);
#pragma unroll
    for (int j = 0; j < 4; j++)
      bfr[j] = *(const bf16x8*)(Bs + (wc + j * 16 + l15) * 32 + lq * 8);
#pragma unroll
    for (int i = 0; i < 4; i++)
#pragma unroll
      for (int j = 0; j < 4; j++)
        acc[i][j] = __builtin_amdgcn_mfma_f32_16x16x32_bf16(af[i], bfr[j], acc[i][j], 0, 0, 0);
  }

#pragma unroll
  for (int j = 0; j < 4; j++) {
    const int col = Nb + wc + j * 16 + l15;
    const float bias = bo[col];
#pragma unroll
    for (int i = 0; i < 4; i++) {
#pragma unroll
      for (int r = 0; r < 4; r++) {
        const int row = Mb + wr + i * 16 + lq * 4 + r;
        out[(size_t)row * DIM + col] = acc[i][j][r] + bias;
      }
    }
  }
}

// ---------------------------------------------------------------------------
extern "C" void kernel_launch(void* const* d_in, const int* in_sizes, int n_in,
                              void* d_out, int out_size, void* d_ws, size_t ws_size,
                              hipStream_t stream) {
  // Reference dtypes: ALL inputs fp32, output fp32.
  const float* q    = (const float*)d_in[0];
  const float* k    = (const float*)d_in[1];
  const float* v    = (const float*)d_in[2];
  const float* wqkv = (const float*)d_in[3];
  const float* bqkv = (const float*)d_in[4];
  const float* wout = (const float*)d_in[5];
  const float* bout = (const float*)d_in[6];

  // ws layout: qkv fp32 (8192x3072) = 100663296 B, then attn bf16 (8192x1024)
  float* qkvws = (float*)d_ws;
  __hip_bfloat16* attnws = (__hip_bfloat16*)((char*)d_ws + (size_t)MROWS * K3 * 4);

  qkv_gemm<<<dim3(K3 / 128, MROWS / 128), 256, 0, stream>>>(q, k, v, wqkv, bqkv, qkvws);
  attn_fwd<<<dim3(4 * HEADS * (SEQ / 64)), 256, 0, stream>>>(qkvws, attnws);
  out_gemm<<<dim3(DIM / 128, MROWS / 128), 256, 0, stream>>>(attnws, wout, bout,
                                                             (float*)d_out);
}

// Round 5
// 1005.984 us; speedup vs baseline: 1.8407x; 1.8407x over previous
//
#include <hip/hip_runtime.h>
#include <hip/hip_bf16.h>

// Problem constants: B=4, N=2048, D=1024, H=16, dh=64. All I/O fp32.
#define SEQ   2048
#define DIM   1024
#define HEADS 16
#define DH    64
#define MROWS 8192            // B*N
#define K3    3072            // 3*D
#define NEGV  (-32767.0f)     // -2^15+1, matches reference mask constant
#define SCALE 8.0f            // sqrt(dh) — reference MULTIPLIES by sqrt(d)

typedef __attribute__((ext_vector_type(8))) short bf16x8;
typedef __attribute__((ext_vector_type(4))) float f32x4;

// bf16 round-to-nearest-even via bit ops (finite inputs only)
__device__ __forceinline__ short f2bf(float x) {
  union { float f; unsigned u; } v; v.f = x;
  unsigned r = v.u + 0x7FFF + ((v.u >> 16) & 1);
  return (short)(r >> 16);
}
__device__ __forceinline__ float bf2f(short s) {
  union { float f; unsigned u; } v; v.u = ((unsigned)(unsigned short)s) << 16;
  return v.f;
}
__device__ __forceinline__ void cvt_split8(const float4 a, const float4 b,
                                           bf16x8& hi, bf16x8& lo) {
  const float f[8] = {a.x, a.y, a.z, a.w, b.x, b.y, b.z, b.w};
#pragma unroll
  for (int i = 0; i < 8; i++) {
    const short h = f2bf(f[i]);
    hi[i] = h;
    lo[i] = f2bf(f[i] - bf2f(h));
  }
}

// XOR-swizzled LDS index (shorts) for 64-col row-major tiles: 8-short (16B)
// blocks permuted by row&7 -> ds_read_b128-able fragments, spread banks.
__device__ __forceinline__ int sw(int row, int col) {
  return row * 64 + ((((col >> 3) ^ row) & 7) << 3) + (col & 7);
}

// ---------------------------------------------------------------------------
// Kernel 1 (unchanged from round 4): qkv = concat(q,k,v) @ w_qkv^T + b_qkv
// Q/K cols split-bf16 3-MFMA compensated; V cols 1-pass.
// ---------------------------------------------------------------------------
__global__ __launch_bounds__(256) void qkv_gemm(
    const float* __restrict__ q,
    const float* __restrict__ k,
    const float* __restrict__ v,
    const float* __restrict__ wqkv,   // (3072, 3072) row-major fp32
    const float* __restrict__ bqkv,   // (3072) fp32
    float* __restrict__ qkvo)         // (8192, 3072) fp32
{
  __shared__ short Ash[128 * 32];
  __shared__ short Asl[128 * 32];
  __shared__ short Bsh[128 * 32];
  __shared__ short Bsl[128 * 32];

  const int t    = threadIdx.x;
  const int lane = t & 63;
  const int wv   = t >> 6;
  const int Mb   = blockIdx.y * 128;
  const int Nb   = blockIdx.x * 128;
  const bool prec = (Nb < 2 * DIM);   // q,k columns need compensation
  const int wr   = (wv >> 1) * 64;
  const int wc   = (wv & 1) * 64;
  const int l15  = lane & 15;
  const int lq   = lane >> 4;
  const int srow = wv * 16 + (lane >> 2);
  const int scol = (lane & 3) * 8;

  f32x4 acc[4][4];
#pragma unroll
  for (int i = 0; i < 4; i++)
#pragma unroll
    for (int j = 0; j < 4; j++) acc[i][j] = (f32x4){0.f, 0.f, 0.f, 0.f};

  for (int k0 = 0; k0 < K3; k0 += 32) {
    const float* src = (k0 < DIM) ? q : ((k0 < 2 * DIM) ? k : v);
    const int koff = (k0 & (DIM - 1)) + scol;

    bf16x8 ah[2], al[2], bh[2], bl[2];
#pragma unroll
    for (int it = 0; it < 2; ++it) {
      const float* ap = src + (size_t)(Mb + it * 64 + srow) * DIM + koff;
      cvt_split8(*(const float4*)(ap), *(const float4*)(ap + 4), ah[it], al[it]);
      const float* bp = wqkv + (size_t)(Nb + it * 64 + srow) * K3 + k0 + scol;
      cvt_split8(*(const float4*)(bp), *(const float4*)(bp + 4), bh[it], bl[it]);
    }
    __syncthreads();
#pragma unroll
    for (int it = 0; it < 2; ++it) {
      *(bf16x8*)(Ash + (it * 64 + srow) * 32 + scol) = ah[it];
      *(bf16x8*)(Bsh + (it * 64 + srow) * 32 + scol) = bh[it];
      if (prec) {
        *(bf16x8*)(Asl + (it * 64 + srow) * 32 + scol) = al[it];
        *(bf16x8*)(Bsl + (it * 64 + srow) * 32 + scol) = bl[it];
      }
    }
    __syncthreads();

    bf16x8 afh[4], bfh[4];
#pragma unroll
    for (int i = 0; i < 4; i++)
      afh[i] = *(const bf16x8*)(Ash + (wr + i * 16 + l15) * 32 + lq * 8);
#pragma unroll
    for (int j = 0; j < 4; j++)
      bfh[j] = *(const bf16x8*)(Bsh + (wc + j * 16 + l15) * 32 + lq * 8);
#pragma unroll
    for (int i = 0; i < 4; i++)
#pragma unroll
      for (int j = 0; j < 4; j++)
        acc[i][j] = __builtin_amdgcn_mfma_f32_16x16x32_bf16(afh[i], bfh[j], acc[i][j], 0, 0, 0);

    if (prec) {
      bf16x8 afl[4], bfl[4];
#pragma unroll
      for (int i = 0; i < 4; i++)
        afl[i] = *(const bf16x8*)(Asl + (wr + i * 16 + l15) * 32 + lq * 8);
#pragma unroll
      for (int j = 0; j < 4; j++)
        bfl[j] = *(const bf16x8*)(Bsl + (wc + j * 16 + l15) * 32 + lq * 8);
#pragma unroll
      for (int i = 0; i < 4; i++)
#pragma unroll
        for (int j = 0; j < 4; j++) {
          acc[i][j] = __builtin_amdgcn_mfma_f32_16x16x32_bf16(afh[i], bfl[j], acc[i][j], 0, 0, 0);
          acc[i][j] = __builtin_amdgcn_mfma_f32_16x16x32_bf16(afl[i], bfh[j], acc[i][j], 0, 0, 0);
        }
    }
  }

#pragma unroll
  for (int j = 0; j < 4; j++) {
    const int col = Nb + wc + j * 16 + l15;
    const float bias = bqkv[col];
#pragma unroll
    for (int i = 0; i < 4; i++) {
#pragma unroll
      for (int r = 0; r < 4; r++) {
        const int row = Mb + wr + i * 16 + lq * 4 + r;
        qkvo[(size_t)row * K3 + col] = acc[i][j][r] + bias;
      }
    }
  }
}

// ---------------------------------------------------------------------------
// Stage 64x64 fp32 tile (row stride K3) -> swizzled hi/lo bf16 LDS.
// Thread t: row=t>>2, cols (t&3)*4 + 16i (i=0..3): global fully coalesced
// (lanes 0-3 = 64B contiguous); LDS writes are 4-short (8B) pieces.
// ---------------------------------------------------------------------------
__device__ __forceinline__ void stage_hl(const float* __restrict__ g0,
                                         short* Hh, short* Hl, int t) {
  const int row = t >> 2;
  const int cb  = (t & 3) * 4;
  const float* gp = g0 + (size_t)row * K3 + cb;
#pragma unroll
  for (int i = 0; i < 4; ++i) {
    const float4 f = *(const float4*)(gp + 16 * i);
    const float fa[4] = {f.x, f.y, f.z, f.w};
    short hi[4], lo[4];
#pragma unroll
    for (int e = 0; e < 4; ++e) {
      hi[e] = f2bf(fa[e]);
      lo[e] = f2bf(fa[e] - bf2f(hi[e]));
    }
    const int off = sw(row, cb + 16 * i);
    *(short4*)(Hh + off) = make_short4(hi[0], hi[1], hi[2], hi[3]);
    *(short4*)(Hl + off) = make_short4(lo[0], lo[1], lo[2], lo[3]);
  }
}

// Stage V 64x64 fp32 (key-major) -> TRANSPOSED swizzled bf16 LDS Vt[d][key].
__device__ __forceinline__ void stage_vt(const float* __restrict__ g0,
                                         short* V, int t) {
  const int key = t >> 2;
  const int db  = (t & 3) * 4;
  const float* gp = g0 + (size_t)key * K3 + db;
#pragma unroll
  for (int i = 0; i < 4; ++i) {
    const float4 f = *(const float4*)(gp + 16 * i);
    const float fa[4] = {f.x, f.y, f.z, f.w};
#pragma unroll
    for (int e = 0; e < 4; ++e)
      V[sw(db + 16 * i + e, key)] = f2bf(fa[e]);
  }
}

// ---------------------------------------------------------------------------
// Kernel 2: MFMA flash attention. Block=(b,h,64-q-tile), 4 waves (16 q-rows
// each). K-tiles of 64 keys. QK^T: split-bf16 3-MFMA (score precision);
// PV: 1-pass bf16 via P->LDS round-trip (C-layout -> A-layout, m120 pattern)
// and swizzle-transposed V. Online softmax in C-layout registers, row state
// replicated across the 16 lanes of each quad-group (shfl_xor 1,2,4,8).
// ---------------------------------------------------------------------------
__global__ __launch_bounds__(256) void attn_fwd(
    const float* __restrict__ qkv,          // (8192, 3072) fp32
    __hip_bfloat16* __restrict__ attno)     // (8192, 1024) bf16
{
  __shared__ short Qh[4096], Ql[4096], Kh[4096], Kl[4096], Vt[4096];
  __shared__ short Ps[4][1024];             // per-wave 16x64 P tile

  const int bx = blockIdx.x;
  const int qt = 31 - (bx & 31);            // heavy q-tiles dispatch first
  const int h  = (bx >> 5) & 15;
  const int b  = bx >> 9;
  const int qb = qt * 64;

  const int t    = threadIdx.x;
  const int lane = t & 63;
  const int wv   = t >> 6;
  const int l15  = lane & 15;
  const int quad = lane >> 4;
  const size_t rowBase = (size_t)b * SEQ;

  stage_hl(qkv + (rowBase + qb) * K3 + h * DH, Qh, Ql, t);
  __syncthreads();

  // Q A-fragments: A[m=l15][k=ks*32+quad*8+j], rows 16*wv + l15 (load once)
  bf16x8 qah[2], qal[2];
#pragma unroll
  for (int ks = 0; ks < 2; ++ks) {
    qah[ks] = *(const bf16x8*)(Qh + sw(16 * wv + l15, ks * 32 + quad * 8));
    qal[ks] = *(const bf16x8*)(Ql + sw(16 * wv + l15, ks * 32 + quad * 8));
  }

  float m_i[4], l_i[4];
  f32x4 O[4];
#pragma unroll
  for (int r = 0; r < 4; ++r) { m_i[r] = -1e30f; l_i[r] = 0.f; }
#pragma unroll
  for (int jd = 0; jd < 4; ++jd) O[jd] = (f32x4){0.f, 0.f, 0.f, 0.f};

  const int nkt = qt + 1;                   // causal: keys <= qb+63
  for (int kt = 0; kt < nkt; ++kt) {
    const int kb = kt * 64;
    __syncthreads();                        // prev tile's fragment reads done
    stage_hl(qkv + (rowBase + kb) * K3 + DIM + h * DH, Kh, Kl, t);
    stage_vt(qkv + (rowBase + kb) * K3 + 2 * DIM + h * DH, Vt, t);
    __syncthreads();                        // staging visible

    // ---- S = Q K^T, 4 n-tiles of 16 keys, split-bf16 (hh + hl + lh) ----
    f32x4 s[4];
#pragma unroll
    for (int j = 0; j < 4; ++j) s[j] = (f32x4){0.f, 0.f, 0.f, 0.f};
#pragma unroll
    for (int j = 0; j < 4; ++j) {
#pragma unroll
      for (int ks = 0; ks < 2; ++ks) {
        const bf16x8 kh = *(const bf16x8*)(Kh + sw(16 * j + l15, ks * 32 + quad * 8));
        const bf16x8 kl = *(const bf16x8*)(Kl + sw(16 * j + l15, ks * 32 + quad * 8));
        s[j] = __builtin_amdgcn_mfma_f32_16x16x32_bf16(qah[ks], kh, s[j], 0, 0, 0);
        s[j] = __builtin_amdgcn_mfma_f32_16x16x32_bf16(qal[ks], kh, s[j], 0, 0, 0);
        s[j] = __builtin_amdgcn_mfma_f32_16x16x32_bf16(qah[ks], kl, s[j], 0, 0, 0);
      }
    }

    // ---- scale, causal mask, online softmax (C-layout registers) ----
    // Lane holds S[row = qb+16wv+4quad+r][key = kb+16j+l15]
    const int qrow0 = qb + 16 * wv + 4 * quad;
    float p[4][4];
    float mt[4] = {-1e30f, -1e30f, -1e30f, -1e30f};
#pragma unroll
    for (int j = 0; j < 4; ++j) {
      const int key = kb + 16 * j + l15;
#pragma unroll
      for (int r = 0; r < 4; ++r) {
        float sv = s[j][r] * SCALE;
        if (key > qrow0 + r) sv = NEGV;
        p[j][r] = sv;
        mt[r] = fmaxf(mt[r], sv);
      }
    }
#pragma unroll
    for (int r = 0; r < 4; ++r) {
      mt[r] = fmaxf(mt[r], __shfl_xor(mt[r], 1));
      mt[r] = fmaxf(mt[r], __shfl_xor(mt[r], 2));
      mt[r] = fmaxf(mt[r], __shfl_xor(mt[r], 4));
      mt[r] = fmaxf(mt[r], __shfl_xor(mt[r], 8));
    }
    float alpha[4];
#pragma unroll
    for (int r = 0; r < 4; ++r) {
      const float mn = fmaxf(m_i[r], mt[r]);
      alpha[r] = __expf(m_i[r] - mn);
      m_i[r] = mn;
    }
    float ls[4] = {0.f, 0.f, 0.f, 0.f};
#pragma unroll
    for (int j = 0; j < 4; ++j)
#pragma unroll
      for (int r = 0; r < 4; ++r) {
        p[j][r] = __expf(p[j][r] - m_i[r]);
        ls[r] += p[j][r];
      }
#pragma unroll
    for (int r = 0; r < 4; ++r) {
      ls[r] += __shfl_xor(ls[r], 1);
      ls[r] += __shfl_xor(ls[r], 2);
      ls[r] += __shfl_xor(ls[r], 4);
      ls[r] += __shfl_xor(ls[r], 8);
      l_i[r] = l_i[r] * alpha[r] + ls[r];
    }
#pragma unroll
    for (int jd = 0; jd < 4; ++jd)
#pragma unroll
      for (int r = 0; r < 4; ++r) O[jd][r] *= alpha[r];

    // ---- P (C-layout) -> per-wave LDS (swizzled row-major 16x64) ----
#pragma unroll
    for (int j = 0; j < 4; ++j)
#pragma unroll
      for (int r = 0; r < 4; ++r)
        Ps[wv][sw(4 * quad + r, 16 * j + l15)] = f2bf(p[j][r]);
    __syncthreads();                        // P visible (conservative)

    // ---- O += P V : A = P (A-layout reload), B = Vt (transposed V) ----
#pragma unroll
    for (int ks = 0; ks < 2; ++ks) {
      const bf16x8 pa = *(const bf16x8*)(&Ps[wv][sw(l15, ks * 32 + quad * 8)]);
#pragma unroll
      for (int jd = 0; jd < 4; ++jd) {
        const bf16x8 vb = *(const bf16x8*)(Vt + sw(16 * jd + l15, ks * 32 + quad * 8));
        O[jd] = __builtin_amdgcn_mfma_f32_16x16x32_bf16(pa, vb, O[jd], 0, 0, 0);
      }
    }
  }

  // epilogue: O/l -> bf16 attn ws (C-layout scatter, once per block)
#pragma unroll
  for (int jd = 0; jd < 4; ++jd) {
#pragma unroll
    for (int r = 0; r < 4; ++r) {
      const int row = qb + 16 * wv + 4 * quad + r;
      attno[(rowBase + row) * DIM + h * DH + 16 * jd + l15] =
          __float2bfloat16(O[jd][r] / l_i[r]);
    }
  }
}

// ---------------------------------------------------------------------------
// Kernel 3 (unchanged from round 4): out = attn @ w_out^T + b_out
// ---------------------------------------------------------------------------
__global__ __launch_bounds__(256) void out_gemm(
    const __hip_bfloat16* __restrict__ a,    // (8192, 1024) attn, bf16
    const float* __restrict__ wo,            // (1024, 1024) fp32
    const float* __restrict__ bo,            // (1024) fp32
    float* __restrict__ out)                 // (8192, 1024) fp32
{
  __shared__ short As[128 * 32];
  __shared__ short Bs[128 * 32];

  const int t    = threadIdx.x;
  const int lane = t & 63;
  const int wv   = t >> 6;
  const int Mb   = blockIdx.y * 128;
  const int Nb   = blockIdx.x * 128;
  const int wr   = (wv >> 1) * 64;
  const int wc   = (wv & 1) * 64;
  const int l15  = lane & 15;
  const int lq   = lane >> 4;
  const int srow = wv * 16 + (lane >> 2);
  const int scol = (lane & 3) * 8;

  f32x4 acc[4][4];
#pragma unroll
  for (int i = 0; i < 4; i++)
#pragma unroll
    for (int j = 0; j < 4; j++) acc[i][j] = (f32x4){0.f, 0.f, 0.f, 0.f};

  for (int k0 = 0; k0 < DIM; k0 += 32) {
    bf16x8 areg[2], breg[2];
#pragma unroll
    for (int it = 0; it < 2; ++it) {
      areg[it] = *(const bf16x8*)(a + (size_t)(Mb + it * 64 + srow) * DIM + k0 + scol);
      const float* bp = wo + (size_t)(Nb + it * 64 + srow) * DIM + k0 + scol;
      const float4 b0 = *(const float4*)(bp);
      const float4 b1 = *(const float4*)(bp + 4);
      const float bf8[8] = {b0.x, b0.y, b0.z, b0.w, b1.x, b1.y, b1.z, b1.w};
#pragma unroll
      for (int e = 0; e < 8; e++) breg[it][e] = f2bf(bf8[e]);
    }
    __syncthreads();
#pragma unroll
    for (int it = 0; it < 2; ++it) {
      *(bf16x8*)(As + (it * 64 + srow) * 32 + scol) = areg[it];
      *(bf16x8*)(Bs + (it * 64 + srow) * 32 + scol) = breg[it];
    }
    __syncthreads();

    bf16x8 af[4], bfr[4];
#pragma unroll
    for (int i = 0; i < 4; i++)
      af[i] = *(const bf16x8*)(As + (wr + i * 16 + l15) * 32 + lq * 8);
#pragma unroll
    for (int j = 0; j < 4; j++)
      bfr[j] = *(const bf16x8*)(Bs + (wc + j * 16 + l15) * 32 + lq * 8);
#pragma unroll
    for (int i = 0; i < 4; i++)
#pragma unroll
      for (int j = 0; j < 4; j++)
        acc[i][j] = __builtin_amdgcn_mfma_f32_16x16x32_bf16(af[i], bfr[j], acc[i][j], 0, 0, 0);
  }

#pragma unroll
  for (int j = 0; j < 4; j++) {
    const int col = Nb + wc + j * 16 + l15;
    const float bias = bo[col];
#pragma unroll
    for (int i = 0; i < 4; i++) {
#pragma unroll
      for (int r = 0; r < 4; r++) {
        const int row = Mb + wr + i * 16 + lq * 4 + r;
        out[(size_t)row * DIM + col] = acc[i][j][r] + bias;
      }
    }
  }
}

// ---------------------------------------------------------------------------
extern "C" void kernel_launch(void* const* d_in, const int* in_sizes, int n_in,
                              void* d_out, int out_size, void* d_ws, size_t ws_size,
                              hipStream_t stream) {
  const float* q    = (const float*)d_in[0];
  const float* k    = (const float*)d_in[1];
  const float* v    = (const float*)d_in[2];
  const float* wqkv = (const float*)d_in[3];
  const float* bqkv = (const float*)d_in[4];
  const float* wout = (const float*)d_in[5];
  const float* bout = (const float*)d_in[6];

  // ws layout: qkv fp32 (8192x3072) = 100663296 B, then attn bf16 (8192x1024)
  float* qkvws = (float*)d_ws;
  __hip_bfloat16* attnws = (__hip_bfloat16*)((char*)d_ws + (size_t)MROWS * K3 * 4);

  qkv_gemm<<<dim3(K3 / 128, MROWS / 128), 256, 0, stream>>>(q, k, v, wqkv, bqkv, qkvws);
  attn_fwd<<<dim3(4 * HEADS * (SEQ / 64)), 256, 0, stream>>>(qkvws, attnws);
  out_gemm<<<dim3(DIM / 128, MROWS / 128), 256, 0, stream>>>(attnws, wout, bout,
                                                             (float*)d_out);
}